// Round 6
// baseline (409.103 us; speedup 1.0000x reference)
//
#include <hip/hip_runtime.h>
#include <cstdint>
#include <cstddef>

// Problem: a[B=4,S=2048,K=4096] int8, w[K=4096,N=4096] int8,
// a_s[8192] f32 per-token scale, w_s[4096] f32 per-col scale.
// out[m][n] = fp16( (int32 dot) * a_s[m] * w_s[n] ), stored as f32 in d_out.
//
// Fragment-order DRAM layout (written by prepare_kernel):
//   A_f byte((m,k)) = ((m>>5)*128 + (k>>5))*1024 + ((m&31) + 32*((k>>4)&1))*16 + (k&15)
//   W_f byte((n,k)) = ((n>>5)*128 + (k>>5))*1024 + ((n&31) + 32*((k>>4)&1))*16 + (k&15)
// Each 1 KiB "region" (32-row block, 32B k-step) is one mfma_i32_32x32x32_i8
// operand tile in lane order: lane l <-> row (l&31), k-half (l>>5).
// GEMM staging loads are 64 lanes x 16B CONTIGUOUS and LDS reads are
// wave-contiguous base + lane*16 (zero bank conflicts — verified R4/R5).

#define M_DIM 8192
#define N_DIM 4096
#define K_DIM 4096

#define PREP_A_BLOCKS ((M_DIM / 32) * (K_DIM / 128))   // 8192
#define PREP_W_BLOCKS ((N_DIM / 64) * (K_DIM / 64))    // 4096

typedef int v4i  __attribute__((ext_vector_type(4)));
typedef int v16i __attribute__((ext_vector_type(16)));

__device__ __forceinline__ uint32_t pack4(int x, int y, int z, int w)
{
    return (uint32_t)(x & 0xff) | ((uint32_t)(y & 0xff) << 8) |
           ((uint32_t)(z & 0xff) << 16) | ((uint32_t)(w & 0xff) << 24);
}

// ---------------------------------------------------------------------------
// Pre-pass — byte-identical to rounds 4/5 (attribution: GEMM-only change).
// ---------------------------------------------------------------------------
__global__ void __launch_bounds__(256) prepare_kernel(
    const int* __restrict__ a, const int* __restrict__ w,
    uint8_t* __restrict__ a_f, uint8_t* __restrict__ w_f)
{
    __shared__ int lds[64][65];
    const int t = threadIdx.x;

    if (blockIdx.x < PREP_A_BLOCKS) {
        uint32_t* l32 = (uint32_t*)&lds[0][0];   // 4KB image, XOR-swizzled
        const int bm = blockIdx.x >> 5;          // 0..255  (32-row block)
        const int bk = blockIdx.x & 31;          // 0..31   (128-col block)
        const int m0 = bm * 32;
        const int k0 = bk * 128;
#pragma unroll
        for (int i = 0; i < 4; ++i) {
            const int f = i * 256 + t;           // int4-group 0..1023 (coalesced)
            const int r = f >> 5;                // row in patch 0..31
            const int c = (f << 2) & 127;        // int32 col in patch (%4==0)
            int4 x = *(const int4*)(a + (size_t)(m0 + r) * K_DIM + k0 + c);
            uint32_t u = pack4(x.x, x.y, x.z, x.w);
            const int region = c >> 5;                       // 0..3
            const int chunk  = r + (((c >> 4) & 1) << 5);    // 0..63
            const int wd     = region * 256 + chunk * 4 + ((c & 15) >> 2);
            l32[wd ^ ((region & 3) << 3)] = u;
        }
        __syncthreads();
        uint4 o = ((const uint4*)l32)[t ^ (((t >> 6) & 3) << 1)];
        *(uint4*)(a_f + ((size_t)bm * 128 + bk * 4) * 1024 + t * 16) = o;
        return;
    }

    // ---- W branch: 64k x 64n tile -> 4 regions (2 n-blocks x 2 k32).
    const int tile = blockIdx.x - PREP_A_BLOCKS;
    const int n0 = (tile & 63) * 64;
    const int k0 = (tile >> 6) * 64;

#pragma unroll
    for (int i = 0; i < 4; ++i) {
        int v   = t + 256 * i;
        int row = v >> 4;              // k within tile
        int cq  = v & 15;              // int4 group within row
        int4 x = *(const int4*)(w + (size_t)(k0 + row) * N_DIM + n0 + cq * 4);
        lds[row][cq * 4 + 0] = x.x;
        lds[row][cq * 4 + 1] = x.y;
        lds[row][cq * 4 + 2] = x.z;
        lds[row][cq * 4 + 3] = x.w;
    }
    __syncthreads();

    const int chunk  = t & 63;         // output chunk within region
    const int r_out  = t >> 6;         // 0..3
    const int nb     = r_out >> 1;     // n-block within tile (0..1)
    const int kk     = r_out & 1;      // k32 within tile (0..1)
    const int ncol   = nb * 32 + (chunk & 31);
    const int parity = chunk >> 5;
    const int rbase  = kk * 32 + parity * 16;
    uint32_t o[4];
#pragma unroll
    for (int q = 0; q < 4; ++q)
        o[q] = pack4(lds[rbase + q * 4 + 0][ncol],
                     lds[rbase + q * 4 + 1][ncol],
                     lds[rbase + q * 4 + 2][ncol],
                     lds[rbase + q * 4 + 3][ncol]);
    *(uint4*)(w_f + (((size_t)(n0 >> 5) + nb) * 128 + (k0 >> 5) + kk) * 1024
                  + chunk * 16) = make_uint4(o[0], o[1], o[2], o[3]);
}

// ---------------------------------------------------------------------------
// int8 GEMM — 256x256 tile, 8 waves, BK=128, double-buffered fragment-order
// LDS.  R6 schedule: ONE vmcnt(0)+s_barrier per K-tile (mid-tile barriers
// carry no dependency: buffer b was fully staged and made visible at the
// previous boundary).  Inside a tile, a ping-pong fragment pipeline
// (afA/bfA vs afB/bfB) issues the ds_reads for k-step s+1 BEFORE the MFMA
// cluster of k-step s — compiler-counted lgkmcnt(6) orders it, and
// sched_barrier(0) pins the group order (rule #18).  LDS-port service of
// step s+1's reads thus overlaps the matrix pipe on step s (in-wave ILP),
// and waves free-run within the tile (cross-wave drift).  Boundary
// vmcnt(0) is near-free: oldest stage issued 4 phases (~2500 cyc) earlier.
// T5 setprio around MFMA clusters; T1 XCD octant swizzle.
// ---------------------------------------------------------------------------
__device__ __forceinline__ void async_copy16(const void* gptr, void* lptr)
{
    __builtin_amdgcn_global_load_lds(
        (const __attribute__((address_space(1))) uint32_t*)gptr,
        (__attribute__((address_space(3))) uint32_t*)lptr,
        16, 0, 0);
}

#define WAIT_VMCNT0() asm volatile("s_waitcnt vmcnt(0)" ::: "memory")
#define SCHED_FENCE() __builtin_amdgcn_sched_barrier(0)

__global__ void __launch_bounds__(512, 2) int8_gemm_kernel(
    const uint8_t* __restrict__ Af,   // fragment-order A (32 MiB)
    const uint8_t* __restrict__ Wf,   // fragment-order W (16 MiB)
    const float*   __restrict__ a_s,  // [M]
    const float*   __restrict__ w_s,  // [N]
    float*         __restrict__ out)  // [M][N] f32 (fp16-rounded)
{
    __shared__ __align__(16) uint8_t sA[2][4][8][1024];
    __shared__ __align__(16) uint8_t sB[2][4][8][1024];

    const int tid   = threadIdx.x;
    const int wave  = tid >> 6;       // 0..7
    const int lane  = tid & 63;
    const int waveM = wave >> 2;      // 0..1  -> 128-row M slab
    const int waveN = wave & 3;       // 0..3  -> 64-col N slab

    // XCD-aware swizzle: 512 blocks, xcd = bid&7 owns an 8x8 (bm,bn) octant.
    const int bid = blockIdx.x;
    const int xc  = bid & 7;
    const int j   = bid >> 3;
    const int bm  = (xc & 3) * 8 + (j & 7);    // 0..31
    const int bn  = (xc >> 2) * 8 + (j >> 3);  // 0..15
    const int m0  = bm * 256;
    const int n0  = bn * 256;

    v16i acc[4][2];
#pragma unroll
    for (int i = 0; i < 4; ++i)
#pragma unroll
        for (int jj = 0; jj < 2; ++jj)
#pragma unroll
            for (int r = 0; r < 16; ++r)
                acc[i][jj][r] = 0;

    // Per-thread staging bases: wave w stages A-region a=w and B-region b=w.
    const uint8_t* aBase = Af + (((size_t)(m0 >> 5) + wave) * 128) * 1024 + lane * 16;
    const uint8_t* bBase = Wf + (((size_t)(n0 >> 5) + wave) * 128) * 1024 + lane * 16;

    auto stage_pair = [&](int buf, int kt, int s) {
        async_copy16(aBase + (size_t)(kt * 4 + s) * 1024, &sA[buf][s][wave][0]);
        async_copy16(bBase + (size_t)(kt * 4 + s) * 1024, &sB[buf][s][wave][0]);
    };

    auto ds_read6 = [&](v4i (&af)[4], v4i (&bf)[2], int buf, int s) {
#pragma unroll
        for (int mt = 0; mt < 4; ++mt)
            af[mt] = *(const v4i*)(&sA[buf][s][waveM * 4 + mt][lane * 16]);
#pragma unroll
        for (int nt = 0; nt < 2; ++nt)
            bf[nt] = *(const v4i*)(&sB[buf][s][waveN * 2 + nt][lane * 16]);
    };

    auto mfma8 = [&](v4i (&af)[4], v4i (&bf)[2]) {
        __builtin_amdgcn_s_setprio(1);
#pragma unroll
        for (int mt = 0; mt < 4; ++mt)
#pragma unroll
            for (int nt = 0; nt < 2; ++nt)
                acc[mt][nt] = __builtin_amdgcn_mfma_i32_32x32x32_i8(
                    af[mt], bf[nt], acc[mt][nt], 0, 0, 0);
        __builtin_amdgcn_s_setprio(0);
    };

    const int NT = K_DIM / 128;       // 32 K-tiles, 4 k-steps each

    // Ping-pong fragment sets (named, statically indexed — rule #20).
    v4i afA[4], bfA[2], afB[4], bfB[2];

    // ---- prologue: stage all of tile 0, make visible, read s0.
#pragma unroll
    for (int s = 0; s < 4; ++s)
        stage_pair(0, 0, s);
    WAIT_VMCNT0();
    SCHED_FENCE();
    __builtin_amdgcn_s_barrier();
    ds_read6(afA, bfA, 0, 0);

    // ---- main loop: 4 k-steps per tile, barrier only at tile boundary.
    for (int kt = 0; kt < NT - 1; ++kt) {
        const int b = kt & 1;
        // s=0: stage(kt+1,0) | read s1 | MFMA s0
        stage_pair(b ^ 1, kt + 1, 0);
        ds_read6(afB, bfB, b, 1);
        SCHED_FENCE();
        mfma8(afA, bfA);
        SCHED_FENCE();
        // s=1
        stage_pair(b ^ 1, kt + 1, 1);
        ds_read6(afA, bfA, b, 2);
        SCHED_FENCE();
        mfma8(afB, bfB);
        SCHED_FENCE();
        // s=2
        stage_pair(b ^ 1, kt + 1, 2);
        ds_read6(afB, bfB, b, 3);
        SCHED_FENCE();
        mfma8(afA, bfA);
        SCHED_FENCE();
        // s=3
        stage_pair(b ^ 1, kt + 1, 3);
        SCHED_FENCE();
        mfma8(afB, bfB);
        SCHED_FENCE();
        // ---- tile boundary: all stages of kt+1 visible to all waves.
        WAIT_VMCNT0();
        SCHED_FENCE();
        __builtin_amdgcn_s_barrier();
        ds_read6(afA, bfA, b ^ 1, 0);
    }

    // ---- last tile: no staging.
    {
        const int b = (NT - 1) & 1;
        ds_read6(afB, bfB, b, 1);
        SCHED_FENCE();
        mfma8(afA, bfA);
        SCHED_FENCE();
        ds_read6(afA, bfA, b, 2);
        SCHED_FENCE();
        mfma8(afB, bfB);
        SCHED_FENCE();
        ds_read6(afB, bfB, b, 3);
        SCHED_FENCE();
        mfma8(afA, bfA);
        SCHED_FENCE();
        mfma8(afB, bfB);
    }

    // ---- epilogue. 32x32 C/D layout: col = lane&31,
    // row = (reg&3) + 8*(reg>>2) + 4*(lane>>5).
    const int col   = lane & 31;
    const int rbase = (lane >> 5) * 4;

#pragma unroll
    for (int mt = 0; mt < 4; ++mt) {
        const int mrow0 = m0 + waveM * 128 + mt * 32 + rbase;
        float asv[16];
#pragma unroll
        for (int reg = 0; reg < 16; ++reg)
            asv[reg] = a_s[mrow0 + (reg & 3) + 8 * (reg >> 2)];
#pragma unroll
        for (int nt = 0; nt < 2; ++nt) {
            const int n = n0 + waveN * 64 + nt * 32 + col;
            const float wsv = w_s[n];
#pragma unroll
            for (int reg = 0; reg < 16; ++reg) {
                const int row = mrow0 + (reg & 3) + 8 * (reg >> 2);
                float v = (float)acc[mt][nt][reg] * asv[reg] * wsv;
                v = (float)(_Float16)v;   // match reference's fp16 cast
                out[(size_t)row * N_DIM + n] = v;
            }
        }
    }
}

// ---------------------------------------------------------------------------
extern "C" void kernel_launch(void* const* d_in, const int* in_sizes, int n_in,
                              void* d_out, int out_size, void* d_ws, size_t ws_size,
                              hipStream_t stream)
{
    const int*   a   = (const int*)  d_in[0];  // int32-widened int8 [8192][4096]
    const float* a_s = (const float*)d_in[1];  // [8192]
    const int*   w   = (const int*)  d_in[2];  // int32-widened int8 [4096][4096]
    const float* w_s = (const float*)d_in[3];  // [4096]
    float*       out = (float*)d_out;

    uint8_t* w_f = (uint8_t*)d_ws;                          // 16 MiB
    uint8_t* a_f = (uint8_t*)d_ws + (size_t)N_DIM * K_DIM;  // 32 MiB

    prepare_kernel<<<PREP_A_BLOCKS + PREP_W_BLOCKS, 256, 0, stream>>>(
        a, w, a_f, w_f);

    int8_gemm_kernel<<<(M_DIM / 256) * (N_DIM / 256), 512, 0, stream>>>(
        a_f, w_f, a_s, w_s, out);
}